// Round 10
// baseline (141.956 us; speedup 1.0000x reference)
//
#include <hip/hip_runtime.h>
#include <stdint.h>

#define B2 128
#define NSEQ 256
#define DIM 256
#define NH 8
#define CH 32

typedef __attribute__((ext_vector_type(8))) __bf16 bf16x8;
typedef __attribute__((ext_vector_type(8))) unsigned short u16x8;
typedef __attribute__((ext_vector_type(4))) unsigned short u16x4;
typedef __attribute__((ext_vector_type(4))) float f32x4;

__device__ __forceinline__ unsigned short f2bf(float f) {
  unsigned int u = __builtin_bit_cast(unsigned int, f);
  u += 0x7FFFu + ((u >> 16) & 1u);
  return (unsigned short)(u >> 16);
}
__device__ __forceinline__ float bf2f(unsigned short h) {
  unsigned int u = ((unsigned int)h) << 16;
  return __builtin_bit_cast(float, u);
}
__device__ __forceinline__ bf16x8 as_bf(u16x8 v) { return __builtin_bit_cast(bf16x8, v); }

__device__ __forceinline__ void gload16(void* lds, const void* g) {
  __builtin_amdgcn_global_load_lds(
      (__attribute__((address_space(1))) void*)(g),
      (__attribute__((address_space(3))) void*)(lds), 16, 0, 0);
}

// ---------------- K0: fp32 -> bf16 conversion ----------------
__global__ void k_convert(const float* __restrict__ x, const float* __restrict__ wqkv,
                          const float* __restrict__ wgate, const float* __restrict__ wo,
                          unsigned short* __restrict__ xb, unsigned short* __restrict__ wallb,
                          unsigned short* __restrict__ wob) {
  const int NX = 8388608, NWALL = 262144, NWO = 65536;
  int i = blockIdx.x * blockDim.x + threadIdx.x;
  int total4 = (NX + NWALL + NWO) >> 2;
  if (i >= total4) return;
  int e = i << 2;
  float4 v;
  unsigned short* dst;
  if (e < NX) {
    v = *reinterpret_cast<const float4*>(x + e);
    dst = xb + e;
  } else if (e < NX + NWALL) {
    int o = e - NX;
    v = (o < 196608) ? *reinterpret_cast<const float4*>(wqkv + o)
                     : *reinterpret_cast<const float4*>(wgate + (o - 196608));
    dst = wallb + o;
  } else {
    int o = e - NX - NWALL;
    v = *reinterpret_cast<const float4*>(wo + o);
    dst = wob + o;
  }
  u16x4 r;
  r[0] = f2bf(v.x); r[1] = f2bf(v.y); r[2] = f2bf(v.z); r[3] = f2bf(v.w);
  *reinterpret_cast<u16x4*>(dst) = r;
}

// ---------------- K1/K3: GEMM  Y = A(bf16) * Bw(bf16)^T ----------------
// BK=32, double-buffered: LDS 32KB -> 4-5 blocks/CU (was 2 at BK=64).
// Swizzle: byte ^= ((row&3)<<4) within each 64B row (4 16B slots).
template <int MODE>
__launch_bounds__(256, 4)
__global__ void k_gemm(const unsigned short* __restrict__ A, const unsigned short* __restrict__ Bw,
                       unsigned short* __restrict__ qs, unsigned short* __restrict__ ksb,
                       unsigned short* __restrict__ vsb, unsigned short* __restrict__ gateb,
                       const float* __restrict__ gbias,
                       float* __restrict__ outp, const float* __restrict__ bo) {
  __shared__ __attribute__((aligned(16))) unsigned short As[2][4096];  // [128][32] bf16, swizzled
  __shared__ __attribute__((aligned(16))) unsigned short Bs[2][4096];
  const int tid = threadIdx.x, lane = tid & 63, w = tid >> 6;
  const int wr = w >> 1, wc = w & 1;
  const int l15 = lane & 15, hi = lane >> 4;
  const int m0 = blockIdx.x * 128, n0 = blockIdx.y * 128;

  auto stage = [&](unsigned short* sbuf, const unsigned short* gsrc, int row0, int k0) {
#pragma unroll
    for (int q2 = 0; q2 < 2; ++q2) {
      int ob = (w * 2 + q2) * 1024 + (lane << 4);  // linear byte offset in 8KB tile
      int r = ob >> 6, cb = ob & 63;
      int scb = cb ^ ((r & 3) << 4);               // inverse-swizzled source slot
      const unsigned short* g = gsrc + (size_t)(row0 + r) * 256 + k0 + (scb >> 1);
      gload16(sbuf + (size_t)(w * 2 + q2) * 512, g);
    }
  };

  f32x4 acc[4][4];
#pragma unroll
  for (int i = 0; i < 4; ++i) {
#pragma unroll
    for (int j = 0; j < 4; ++j) acc[i][j] = (f32x4){0.f, 0.f, 0.f, 0.f};
  }

  stage(As[0], A, m0, 0);
  stage(Bs[0], Bw, n0, 0);
  asm volatile("s_waitcnt vmcnt(0)" ::: "memory");
  __syncthreads();

#pragma unroll
  for (int kt = 0; kt < 8; ++kt) {
    const int cur = kt & 1;
    if (kt < 7) {
      stage(As[cur ^ 1], A, m0, (kt + 1) * 32);
      stage(Bs[cur ^ 1], Bw, n0, (kt + 1) * 32);
    }
    {
      bf16x8 af[4], bfv[4];
      const int cbx = hi << 4;  // 16B col-slot within 64B row
#pragma unroll
      for (int fr = 0; fr < 4; ++fr) {
        int ra = wr * 64 + fr * 16 + l15;
        int off = ra * 64 + (cbx ^ ((ra & 3) << 4));
        af[fr] = *reinterpret_cast<const bf16x8*>((const char*)As[cur] + off);
      }
#pragma unroll
      for (int fc = 0; fc < 4; ++fc) {
        int rb = wc * 64 + fc * 16 + l15;
        int off = rb * 64 + (cbx ^ ((rb & 3) << 4));
        bfv[fc] = *reinterpret_cast<const bf16x8*>((const char*)Bs[cur] + off);
      }
#pragma unroll
      for (int fr = 0; fr < 4; ++fr) {
#pragma unroll
        for (int fc = 0; fc < 4; ++fc)
          acc[fr][fc] = __builtin_amdgcn_mfma_f32_16x16x32_bf16(af[fr], bfv[fc], acc[fr][fc], 0, 0, 0);
      }
    }
    asm volatile("s_waitcnt vmcnt(0)" ::: "memory");
    __syncthreads();
  }

  if (MODE == 0) {
#pragma unroll
    for (int fr = 0; fr < 4; ++fr) {
      int mrow = m0 + wr * 64 + fr * 16 + (hi << 2);
      int b = mrow >> 8, n = mrow & 255;
#pragma unroll
      for (int fc = 0; fc < 4; ++fc) {
        int e = n0 + wc * 64 + fc * 16 + l15;
        int which = e >> 8, loc = e & 255, hh = loc >> 5, cc = loc & 31;
#pragma unroll
        for (int i = 0; i < 4; ++i) {
          float v = acc[fr][fc][i];
          size_t idx = ((size_t)(b * 8 + hh) * 256 + (n + i)) * 32 + cc;
          if (which == 0) {
            qs[idx] = f2bf(v * 0.17677669529663687f);  // C^-0.5
          } else if (which == 1) {
            ksb[idx] = f2bf(v);
          } else if (which == 2) {
            vsb[idx] = f2bf(v);
          } else {
            float gsig = 1.0f / (1.0f + __expf(-(v + gbias[loc])));
            gateb[idx] = f2bf(gsig);  // [bh][n][c] layout, same as q/k/v
          }
        }
      }
    }
  } else {
#pragma unroll
    for (int fr = 0; fr < 4; ++fr) {
      int mrow = m0 + wr * 64 + fr * 16 + (hi << 2);
#pragma unroll
      for (int fc = 0; fc < 4; ++fc) {
        int e = n0 + wc * 64 + fc * 16 + l15;
        float bb = bo[e];
#pragma unroll
        for (int i = 0; i < 4; ++i)
          outp[(size_t)(mrow + i) * 256 + e] = acc[fr][fc][i] + bb;
      }
    }
  }
}

// ---------------- K2: attention per (b2, head), transposed-S layout ----------------
// K fragments loaded from global ONCE per block and pinned in VGPRs (asm "+v"
// defeats rematerialization/sinking). LDS 36.6KB -> more resident blocks.
__launch_bounds__(256, 3)
__global__ void k_attn(const unsigned short* __restrict__ qs, const unsigned short* __restrict__ ksb,
                       const unsigned short* __restrict__ vsb, const unsigned short* __restrict__ gateb,
                       const float* __restrict__ mask, const float* __restrict__ nb,
                       unsigned short* __restrict__ wag) {
  __shared__ __attribute__((aligned(16))) unsigned short vt[32][264];        // V^T [c][key]
  __shared__ __attribute__((aligned(16))) unsigned short pch[4][2][16][72];  // per-wave P chunks
  __shared__ __attribute__((aligned(16))) float mb[256];
  __shared__ float invl[4][16];
  const int tid = threadIdx.x, lane = tid & 63, w = tid >> 6;
  const int l15 = lane & 15, hi = lane >> 4;
  const int b = blockIdx.x, h = blockIdx.y;
  const size_t bh = (size_t)(b * 8 + h);
  const unsigned short* kbase = ksb + bh * 8192;
  const unsigned short* vbase = vsb + bh * 8192;
  const unsigned short* qbase = qs + bh * 8192;
  const float* nbh = nb + (size_t)h * 65536;

  mb[tid] = 1e9f * (mask[b * 256 + tid] - 1.0f);
  {
    const unsigned short* vrow = vbase + tid * 32;
#pragma unroll
    for (int c0 = 0; c0 < 32; c0 += 8) {
      u16x8 vv = *reinterpret_cast<const u16x8*>(vrow + c0);
#pragma unroll
      for (int j = 0; j < 8; ++j) vt[c0 + j][tid] = vv[j];
    }
  }
  // K fragments: load once, pin in registers for all 4 fr iterations.
  u16x8 kfu[16];
#pragma unroll
  for (int kt = 0; kt < 16; ++kt) {
    kfu[kt] = *reinterpret_cast<const u16x8*>(kbase + (kt * 16 + l15) * 32 + hi * 8);
    asm volatile("" : "+v"(kfu[kt]));
  }
  __syncthreads();

  const f32x4 zero = {0.f, 0.f, 0.f, 0.f};
#pragma unroll 1
  for (int fr = 0; fr < 4; ++fr) {
    const int q0 = w * 64 + fr * 16;
    u16x8 qf = *reinterpret_cast<const u16x8*>(qbase + (q0 + l15) * 32 + hi * 8);

    f32x4 sacc[16];
    __builtin_amdgcn_s_setprio(1);
#pragma unroll
    for (int kt = 0; kt < 16; ++kt)
      sacc[kt] = __builtin_amdgcn_mfma_f32_16x16x32_bf16(as_bf(kfu[kt]), as_bf(qf), zero, 0, 0, 0);
    __builtin_amdgcn_s_setprio(0);

    const float* nbq = nbh + (size_t)(q0 + l15) * 256;
#pragma unroll
    for (int kt = 0; kt < 16; ++kt) {
      float4 nb4 = *reinterpret_cast<const float4*>(nbq + kt * 16 + hi * 4);
      float4 mb4 = *reinterpret_cast<const float4*>(&mb[kt * 16 + hi * 4]);
      sacc[kt][0] += mb4.x + nb4.x;
      sacc[kt][1] += mb4.y + nb4.y;
      sacc[kt][2] += mb4.z + nb4.z;
      sacc[kt][3] += mb4.w + nb4.w;
    }
    float mx = -3.0e38f;
#pragma unroll
    for (int kt = 0; kt < 16; ++kt) {
#pragma unroll
      for (int i = 0; i < 4; ++i) mx = fmaxf(mx, sacc[kt][i]);
    }
    mx = fmaxf(mx, __shfl_xor(mx, 16));
    mx = fmaxf(mx, __shfl_xor(mx, 32));

    float sum = 0.f;
    f32x4 wacc[2];
    wacc[0] = zero; wacc[1] = zero;
#pragma unroll
    for (int c = 0; c < 4; ++c) {
      const int buf = c & 1;
#pragma unroll
      for (int ktl = 0; ktl < 4; ++ktl) {
        const int kt = c * 4 + ktl;
        u16x4 pv;
#pragma unroll
        for (int i = 0; i < 4; ++i) {
          float p = __expf(sacc[kt][i] - mx);
          sum += p;
          pv[i] = f2bf(p);  // unnormalized; inv folded into epilogue
        }
        *reinterpret_cast<u16x4*>(&pch[w][buf][l15][ktl * 16 + hi * 4]) = pv;
      }
      asm volatile("s_waitcnt lgkmcnt(0)" ::: "memory");
      __builtin_amdgcn_sched_barrier(0);
      __builtin_amdgcn_s_setprio(1);
#pragma unroll
      for (int ks2 = 0; ks2 < 2; ++ks2) {
        bf16x8 pa = *reinterpret_cast<const bf16x8*>(&pch[w][buf][l15][ks2 * 32 + hi * 8]);
#pragma unroll
        for (int ct = 0; ct < 2; ++ct) {
          bf16x8 vb = *reinterpret_cast<const bf16x8*>(&vt[ct * 16 + l15][c * 64 + ks2 * 32 + hi * 8]);
          wacc[ct] = __builtin_amdgcn_mfma_f32_16x16x32_bf16(pa, vb, wacc[ct], 0, 0, 0);
        }
      }
      __builtin_amdgcn_s_setprio(0);
    }
    sum += __shfl_xor(sum, 16);
    sum += __shfl_xor(sum, 32);
    const float inv = 1.0f / sum;
    if (hi == 0) invl[w][l15] = inv;

    // Epilogue: transpose wacc through LDS (reuse pch[w] buf0 area as [16][36] f32)
    float* et = reinterpret_cast<float*>(&pch[w][0][0][0]);
#pragma unroll
    for (int ct = 0; ct < 2; ++ct) {
#pragma unroll
      for (int i = 0; i < 4; ++i)
        et[(hi * 4 + i) * 36 + ct * 16 + l15] = wacc[ct][i];
    }
    asm volatile("s_waitcnt lgkmcnt(0)" ::: "memory");
    __builtin_amdgcn_sched_barrier(0);
    const int eq = lane >> 2, eh = lane & 3;
    float4 v0 = *reinterpret_cast<const float4*>(&et[eq * 36 + eh * 8]);
    float4 v1 = *reinterpret_cast<const float4*>(&et[eq * 36 + eh * 8 + 4]);
    const float iv = invl[w][eq];
    const int qrow = q0 + eq;
    u16x8 g = *reinterpret_cast<const u16x8*>(gateb + bh * 8192 + qrow * 32 + eh * 8);
    u16x8 ov;
    ov[0] = f2bf(bf2f(g[0]) * v0.x * iv);
    ov[1] = f2bf(bf2f(g[1]) * v0.y * iv);
    ov[2] = f2bf(bf2f(g[2]) * v0.z * iv);
    ov[3] = f2bf(bf2f(g[3]) * v0.w * iv);
    ov[4] = f2bf(bf2f(g[4]) * v1.x * iv);
    ov[5] = f2bf(bf2f(g[5]) * v1.y * iv);
    ov[6] = f2bf(bf2f(g[6]) * v1.z * iv);
    ov[7] = f2bf(bf2f(g[7]) * v1.w * iv);
    *reinterpret_cast<u16x8*>(wag + ((size_t)(b * 256 + qrow)) * 256 + h * 32 + eh * 8) = ov;
    asm volatile("s_waitcnt lgkmcnt(0)" ::: "memory");  // drain et reads before next fr reuses pch
    __builtin_amdgcn_sched_barrier(0);
  }
}

extern "C" void kernel_launch(void* const* d_in, const int* in_sizes, int n_in,
                              void* d_out, int out_size, void* d_ws, size_t ws_size,
                              hipStream_t stream) {
  const float* x     = (const float*)d_in[0];
  const float* mask  = (const float*)d_in[1];
  const float* nb    = (const float*)d_in[2];
  const float* wqkv  = (const float*)d_in[3];
  const float* wgate = (const float*)d_in[4];
  const float* gbias = (const float*)d_in[5];
  const float* wo    = (const float*)d_in[6];
  const float* bo    = (const float*)d_in[7];
  float* outp = (float*)d_out;

  char* ws = (char*)d_ws;
  unsigned short* xb    = (unsigned short*)(ws);               // 16,777,216 B
  unsigned short* wallb = (unsigned short*)(ws + 16777216);    //    524,288 B
  unsigned short* wob   = (unsigned short*)(ws + 17301504);    //    131,072 B
  unsigned short* qs    = (unsigned short*)(ws + 17432576);    // 16,777,216 B
  unsigned short* ksb   = (unsigned short*)(ws + 34209792);    // 16,777,216 B
  unsigned short* vsb   = (unsigned short*)(ws + 50987008);    // 16,777,216 B
  unsigned short* gateb = (unsigned short*)(ws + 67764224);    // 16,777,216 B
  unsigned short* wag   = xb;  // alias: x_bf dead after K1

  k_convert<<<dim3(8512), dim3(256), 0, stream>>>(x, wqkv, wgate, wo, xb, wallb, wob);
  k_gemm<0><<<dim3(256, 8), dim3(256), 0, stream>>>(xb, wallb, qs, ksb, vsb, gateb, gbias, nullptr, nullptr);
  k_attn<<<dim3(128, 8), dim3(256), 0, stream>>>(qs, ksb, vsb, gateb, mask, nb, wag);
  k_gemm<1><<<dim3(256, 2), dim3(256), 0, stream>>>(wag, wob, nullptr, nullptr, nullptr, nullptr, nullptr, outp, bo);
}

// Round 11
// 132.740 us; speedup vs baseline: 1.0694x; 1.0694x over previous
//
#include <hip/hip_runtime.h>
#include <stdint.h>

#define B2 128
#define NSEQ 256
#define DIM 256
#define NH 8
#define CH 32

typedef __attribute__((ext_vector_type(8))) __bf16 bf16x8;
typedef __attribute__((ext_vector_type(8))) unsigned short u16x8;
typedef __attribute__((ext_vector_type(4))) unsigned short u16x4;
typedef __attribute__((ext_vector_type(4))) float f32x4;

__device__ __forceinline__ unsigned short f2bf(float f) {
  unsigned int u = __builtin_bit_cast(unsigned int, f);
  u += 0x7FFFu + ((u >> 16) & 1u);
  return (unsigned short)(u >> 16);
}
__device__ __forceinline__ float bf2f(unsigned short h) {
  unsigned int u = ((unsigned int)h) << 16;
  return __builtin_bit_cast(float, u);
}
__device__ __forceinline__ bf16x8 as_bf(u16x8 v) { return __builtin_bit_cast(bf16x8, v); }

__device__ __forceinline__ void gload16(void* lds, const void* g) {
  __builtin_amdgcn_global_load_lds(
      (__attribute__((address_space(1))) void*)(g),
      (__attribute__((address_space(3))) void*)(lds), 16, 0, 0);
}

// ---------------- K0: fp32 -> bf16 conversion ----------------
__global__ void k_convert(const float* __restrict__ x, const float* __restrict__ wqkv,
                          const float* __restrict__ wgate, const float* __restrict__ wo,
                          unsigned short* __restrict__ xb, unsigned short* __restrict__ wallb,
                          unsigned short* __restrict__ wob) {
  const int NX = 8388608, NWALL = 262144, NWO = 65536;
  int i = blockIdx.x * blockDim.x + threadIdx.x;
  int total4 = (NX + NWALL + NWO) >> 2;
  if (i >= total4) return;
  int e = i << 2;
  float4 v;
  unsigned short* dst;
  if (e < NX) {
    v = *reinterpret_cast<const float4*>(x + e);
    dst = xb + e;
  } else if (e < NX + NWALL) {
    int o = e - NX;
    v = (o < 196608) ? *reinterpret_cast<const float4*>(wqkv + o)
                     : *reinterpret_cast<const float4*>(wgate + (o - 196608));
    dst = wallb + o;
  } else {
    int o = e - NX - NWALL;
    v = *reinterpret_cast<const float4*>(wo + o);
    dst = wob + o;
  }
  u16x4 r;
  r[0] = f2bf(v.x); r[1] = f2bf(v.y); r[2] = f2bf(v.z); r[3] = f2bf(v.w);
  *reinterpret_cast<u16x4*>(dst) = r;
}

// ---------------- K1/K3: GEMM  Y = A(bf16) * Bw(bf16)^T ----------------
// BK=32, double-buffered: LDS 32KB. Swizzle: byte ^= ((row&3)<<4) per 64B row.
template <int MODE>
__launch_bounds__(256, 4)
__global__ void k_gemm(const unsigned short* __restrict__ A, const unsigned short* __restrict__ Bw,
                       unsigned short* __restrict__ qs, unsigned short* __restrict__ ksb,
                       unsigned short* __restrict__ vsb, unsigned short* __restrict__ gateb,
                       const float* __restrict__ gbias,
                       float* __restrict__ outp, const float* __restrict__ bo) {
  __shared__ __attribute__((aligned(16))) unsigned short As[2][4096];  // [128][32] bf16, swizzled
  __shared__ __attribute__((aligned(16))) unsigned short Bs[2][4096];
  const int tid = threadIdx.x, lane = tid & 63, w = tid >> 6;
  const int wr = w >> 1, wc = w & 1;
  const int l15 = lane & 15, hi = lane >> 4;
  const int m0 = blockIdx.x * 128, n0 = blockIdx.y * 128;

  auto stage = [&](unsigned short* sbuf, const unsigned short* gsrc, int row0, int k0) {
#pragma unroll
    for (int q2 = 0; q2 < 2; ++q2) {
      int ob = (w * 2 + q2) * 1024 + (lane << 4);  // linear byte offset in 8KB tile
      int r = ob >> 6, cb = ob & 63;
      int scb = cb ^ ((r & 3) << 4);               // inverse-swizzled source slot
      const unsigned short* g = gsrc + (size_t)(row0 + r) * 256 + k0 + (scb >> 1);
      gload16(sbuf + (size_t)(w * 2 + q2) * 512, g);
    }
  };

  f32x4 acc[4][4];
#pragma unroll
  for (int i = 0; i < 4; ++i) {
#pragma unroll
    for (int j = 0; j < 4; ++j) acc[i][j] = (f32x4){0.f, 0.f, 0.f, 0.f};
  }

  stage(As[0], A, m0, 0);
  stage(Bs[0], Bw, n0, 0);
  asm volatile("s_waitcnt vmcnt(0)" ::: "memory");
  __syncthreads();

#pragma unroll
  for (int kt = 0; kt < 8; ++kt) {
    const int cur = kt & 1;
    if (kt < 7) {
      stage(As[cur ^ 1], A, m0, (kt + 1) * 32);
      stage(Bs[cur ^ 1], Bw, n0, (kt + 1) * 32);
    }
    {
      bf16x8 af[4], bfv[4];
      const int cbx = hi << 4;  // 16B col-slot within 64B row
#pragma unroll
      for (int fr = 0; fr < 4; ++fr) {
        int ra = wr * 64 + fr * 16 + l15;
        int off = ra * 64 + (cbx ^ ((ra & 3) << 4));
        af[fr] = *reinterpret_cast<const bf16x8*>((const char*)As[cur] + off);
      }
#pragma unroll
      for (int fc = 0; fc < 4; ++fc) {
        int rb = wc * 64 + fc * 16 + l15;
        int off = rb * 64 + (cbx ^ ((rb & 3) << 4));
        bfv[fc] = *reinterpret_cast<const bf16x8*>((const char*)Bs[cur] + off);
      }
#pragma unroll
      for (int fr = 0; fr < 4; ++fr) {
#pragma unroll
        for (int fc = 0; fc < 4; ++fc)
          acc[fr][fc] = __builtin_amdgcn_mfma_f32_16x16x32_bf16(af[fr], bfv[fc], acc[fr][fc], 0, 0, 0);
      }
    }
    asm volatile("s_waitcnt vmcnt(0)" ::: "memory");
    __syncthreads();
  }

  if (MODE == 0) {
#pragma unroll
    for (int fr = 0; fr < 4; ++fr) {
      int mrow = m0 + wr * 64 + fr * 16 + (hi << 2);
      int b = mrow >> 8, n = mrow & 255;
#pragma unroll
      for (int fc = 0; fc < 4; ++fc) {
        int e = n0 + wc * 64 + fc * 16 + l15;
        int which = e >> 8, loc = e & 255, hh = loc >> 5, cc = loc & 31;
#pragma unroll
        for (int i = 0; i < 4; ++i) {
          float v = acc[fr][fc][i];
          size_t idx = ((size_t)(b * 8 + hh) * 256 + (n + i)) * 32 + cc;
          if (which == 0) {
            qs[idx] = f2bf(v * 0.17677669529663687f);  // C^-0.5
          } else if (which == 1) {
            ksb[idx] = f2bf(v);
          } else if (which == 2) {
            vsb[idx] = f2bf(v);
          } else {
            float gsig = 1.0f / (1.0f + __expf(-(v + gbias[loc])));
            gateb[idx] = f2bf(gsig);  // [bh][n][c] layout, same as q/k/v
          }
        }
      }
    }
  } else {
#pragma unroll
    for (int fr = 0; fr < 4; ++fr) {
      int mrow = m0 + wr * 64 + fr * 16 + (hi << 2);
#pragma unroll
      for (int fc = 0; fc < 4; ++fc) {
        int e = n0 + wc * 64 + fc * 16 + l15;
        float bb = bo[e];
#pragma unroll
        for (int i = 0; i < 4; ++i)
          outp[(size_t)(mrow + i) * 256 + e] = acc[fr][fc][i] + bb;
      }
    }
  }
}

// ---------------- K2: attention per (b2, head, q-half) ----------------
// Transposed-S (mfma(K,Q)). K fragments in LDS with LANE-LINEAR layout
// Kl[kt][lane][8] -> each wave's kf read is contiguous 1024B (conflict-free).
// Query-split: blockIdx.z picks 128-query half; 2 fr iterations per wave.
// pch single-buffered (per-wave DS FIFO makes WAR safe).
__launch_bounds__(256, 3)
__global__ void k_attn(const unsigned short* __restrict__ qs, const unsigned short* __restrict__ ksb,
                       const unsigned short* __restrict__ vsb, const unsigned short* __restrict__ gateb,
                       const float* __restrict__ mask, const float* __restrict__ nb,
                       unsigned short* __restrict__ wag) {
  __shared__ __attribute__((aligned(16))) unsigned short vt[32][264];     // V^T [c][key]
  __shared__ __attribute__((aligned(16))) unsigned short pch[4][16][72];  // per-wave P chunk (64 keys)
  __shared__ __attribute__((aligned(16))) unsigned short Kl[16][64][8];   // K frags, lane-linear
  __shared__ __attribute__((aligned(16))) float mb[256];
  __shared__ float invl[4][16];
  const int tid = threadIdx.x, lane = tid & 63, w = tid >> 6;
  const int l15 = lane & 15, hi = lane >> 4;
  const int b = blockIdx.x, h = blockIdx.y, qz = blockIdx.z;
  const size_t bh = (size_t)(b * 8 + h);
  const unsigned short* kbase = ksb + bh * 8192;
  const unsigned short* vbase = vsb + bh * 8192;
  const unsigned short* qbase = qs + bh * 8192;
  const float* nbh = nb + (size_t)h * 65536;

  mb[tid] = 1e9f * (mask[b * 256 + tid] - 1.0f);
  {
    const unsigned short* vrow = vbase + tid * 32;
#pragma unroll
    for (int c0 = 0; c0 < 32; c0 += 8) {
      u16x8 vv = *reinterpret_cast<const u16x8*>(vrow + c0);
#pragma unroll
      for (int j = 0; j < 8; ++j) vt[c0 + j][tid] = vv[j];
    }
    // K row tid -> Kl[tid>>4][c8*16 + (tid&15)]  (fragment lane = hi*16+l15)
    const unsigned short* krow = kbase + tid * 32;
#pragma unroll
    for (int c8 = 0; c8 < 4; ++c8)
      *reinterpret_cast<u16x8*>(&Kl[tid >> 4][c8 * 16 + (tid & 15)][0]) =
          *reinterpret_cast<const u16x8*>(krow + c8 * 8);
  }
  __syncthreads();

  const f32x4 zero = {0.f, 0.f, 0.f, 0.f};
#pragma unroll 1
  for (int fr = 0; fr < 2; ++fr) {
    const int q0 = qz * 128 + w * 32 + fr * 16;
    u16x8 qf = *reinterpret_cast<const u16x8*>(qbase + (q0 + l15) * 32 + hi * 8);

    f32x4 sacc[16];
    __builtin_amdgcn_s_setprio(1);
#pragma unroll
    for (int kt = 0; kt < 16; ++kt) {
      bf16x8 kf = *reinterpret_cast<const bf16x8*>(&Kl[kt][lane][0]);
      sacc[kt] = __builtin_amdgcn_mfma_f32_16x16x32_bf16(kf, as_bf(qf), zero, 0, 0, 0);
    }
    __builtin_amdgcn_s_setprio(0);

    const float* nbq = nbh + (size_t)(q0 + l15) * 256;
#pragma unroll
    for (int kt = 0; kt < 16; ++kt) {
      float4 nb4 = *reinterpret_cast<const float4*>(nbq + kt * 16 + hi * 4);
      float4 mb4 = *reinterpret_cast<const float4*>(&mb[kt * 16 + hi * 4]);
      sacc[kt][0] += mb4.x + nb4.x;
      sacc[kt][1] += mb4.y + nb4.y;
      sacc[kt][2] += mb4.z + nb4.z;
      sacc[kt][3] += mb4.w + nb4.w;
    }
    float mx = -3.0e38f;
#pragma unroll
    for (int kt = 0; kt < 16; ++kt) {
#pragma unroll
      for (int i = 0; i < 4; ++i) mx = fmaxf(mx, sacc[kt][i]);
    }
    mx = fmaxf(mx, __shfl_xor(mx, 16));
    mx = fmaxf(mx, __shfl_xor(mx, 32));

    float sum = 0.f;
    f32x4 wacc[2];
    wacc[0] = zero; wacc[1] = zero;
#pragma unroll
    for (int c = 0; c < 4; ++c) {
#pragma unroll
      for (int ktl = 0; ktl < 4; ++ktl) {
        const int kt = c * 4 + ktl;
        u16x4 pv;
#pragma unroll
        for (int i = 0; i < 4; ++i) {
          float p = __expf(sacc[kt][i] - mx);
          sum += p;
          pv[i] = f2bf(p);  // unnormalized; inv folded into epilogue
        }
        *reinterpret_cast<u16x4*>(&pch[w][l15][ktl * 16 + hi * 4]) = pv;
      }
      asm volatile("s_waitcnt lgkmcnt(0)" ::: "memory");
      __builtin_amdgcn_sched_barrier(0);
      __builtin_amdgcn_s_setprio(1);
#pragma unroll
      for (int ks2 = 0; ks2 < 2; ++ks2) {
        bf16x8 pa = *reinterpret_cast<const bf16x8*>(&pch[w][l15][ks2 * 32 + hi * 8]);
#pragma unroll
        for (int ct = 0; ct < 2; ++ct) {
          bf16x8 vb = *reinterpret_cast<const bf16x8*>(&vt[ct * 16 + l15][c * 64 + ks2 * 32 + hi * 8]);
          wacc[ct] = __builtin_amdgcn_mfma_f32_16x16x32_bf16(pa, vb, wacc[ct], 0, 0, 0);
        }
      }
      __builtin_amdgcn_s_setprio(0);
    }
    sum += __shfl_xor(sum, 16);
    sum += __shfl_xor(sum, 32);
    const float inv = 1.0f / sum;
    if (hi == 0) invl[w][l15] = inv;

    // Epilogue: transpose wacc through LDS (reuse pch[w] as [16][36] f32)
    float* et = reinterpret_cast<float*>(&pch[w][0][0]);
#pragma unroll
    for (int ct = 0; ct < 2; ++ct) {
#pragma unroll
      for (int i = 0; i < 4; ++i)
        et[(hi * 4 + i) * 36 + ct * 16 + l15] = wacc[ct][i];
    }
    asm volatile("s_waitcnt lgkmcnt(0)" ::: "memory");
    __builtin_amdgcn_sched_barrier(0);
    const int eq = lane >> 2, eh = lane & 3;
    float4 v0 = *reinterpret_cast<const float4*>(&et[eq * 36 + eh * 8]);
    float4 v1 = *reinterpret_cast<const float4*>(&et[eq * 36 + eh * 8 + 4]);
    const float iv = invl[w][eq];
    const int qrow = q0 + eq;
    u16x8 g = *reinterpret_cast<const u16x8*>(gateb + bh * 8192 + qrow * 32 + eh * 8);
    u16x8 ov;
    ov[0] = f2bf(bf2f(g[0]) * v0.x * iv);
    ov[1] = f2bf(bf2f(g[1]) * v0.y * iv);
    ov[2] = f2bf(bf2f(g[2]) * v0.z * iv);
    ov[3] = f2bf(bf2f(g[3]) * v0.w * iv);
    ov[4] = f2bf(bf2f(g[4]) * v1.x * iv);
    ov[5] = f2bf(bf2f(g[5]) * v1.y * iv);
    ov[6] = f2bf(bf2f(g[6]) * v1.z * iv);
    ov[7] = f2bf(bf2f(g[7]) * v1.w * iv);
    *reinterpret_cast<u16x8*>(wag + ((size_t)(b * 256 + qrow)) * 256 + h * 32 + eh * 8) = ov;
    asm volatile("s_waitcnt lgkmcnt(0)" ::: "memory");  // drain et reads before next fr reuses pch
    __builtin_amdgcn_sched_barrier(0);
  }
}

extern "C" void kernel_launch(void* const* d_in, const int* in_sizes, int n_in,
                              void* d_out, int out_size, void* d_ws, size_t ws_size,
                              hipStream_t stream) {
  const float* x     = (const float*)d_in[0];
  const float* mask  = (const float*)d_in[1];
  const float* nb    = (const float*)d_in[2];
  const float* wqkv  = (const float*)d_in[3];
  const float* wgate = (const float*)d_in[4];
  const float* gbias = (const float*)d_in[5];
  const float* wo    = (const float*)d_in[6];
  const float* bo    = (const float*)d_in[7];
  float* outp = (float*)d_out;

  char* ws = (char*)d_ws;
  unsigned short* xb    = (unsigned short*)(ws);               // 16,777,216 B
  unsigned short* wallb = (unsigned short*)(ws + 16777216);    //    524,288 B
  unsigned short* wob   = (unsigned short*)(ws + 17301504);    //    131,072 B
  unsigned short* qs    = (unsigned short*)(ws + 17432576);    // 16,777,216 B
  unsigned short* ksb   = (unsigned short*)(ws + 34209792);    // 16,777,216 B
  unsigned short* vsb   = (unsigned short*)(ws + 50987008);    // 16,777,216 B
  unsigned short* gateb = (unsigned short*)(ws + 67764224);    // 16,777,216 B
  unsigned short* wag   = xb;  // alias: x_bf dead after K1

  k_convert<<<dim3(8512), dim3(256), 0, stream>>>(x, wqkv, wgate, wo, xb, wallb, wob);
  k_gemm<0><<<dim3(256, 8), dim3(256), 0, stream>>>(xb, wallb, qs, ksb, vsb, gateb, gbias, nullptr, nullptr);
  k_attn<<<dim3(128, 8, 2), dim3(256), 0, stream>>>(qs, ksb, vsb, gateb, mask, nb, wag);
  k_gemm<1><<<dim3(256, 2), dim3(256), 0, stream>>>(wag, wob, nullptr, nullptr, nullptr, nullptr, nullptr, outp, bo);
}